// Round 1
// baseline (17850.252 us; speedup 1.0000x reference)
//
#include <hip/hip_runtime.h>

#define NT 512
#define ND 256
#define NH 1024
#define NB 64

// Grid: 256 wgs = 8 batch-groups (8 batches each) x 32 H-slices (32 rows each).
// Block: 256 threads = 4 waves; wave w owns rows w*8..w*8+7 of the slice,
// lane kc (0..63) owns k-values {kc*4 + j*256 + m : j<4, m<4} (conflict-free b128 LDS reads).
__global__ void __launch_bounds__(256, 1)
rnn_step_kernel(const float* __restrict__ x,
                const float* __restrict__ Wx_w,
                const float* __restrict__ Wx_b,
                const float* __restrict__ Wh_w,
                const float* __restrict__ Ws_w,
                const float* __restrict__ Ws_b,
                const float* __restrict__ Us_w,
                const float* __restrict__ out_w,
                float* __restrict__ out,
                float* __restrict__ hbuf,
                unsigned int* __restrict__ flags)
{
  const int tid = (int)threadIdx.x;
  const int w   = tid >> 6;        // wave 0..3
  const int kc  = tid & 63;        // lane
  const int bid = (int)blockIdx.x;
  const int sl  = bid & 31;        // H-slice
  const int bg  = bid >> 5;        // batch group
  const int r_base = sl * 32;
  const int b_base = bg * 8;

  __shared__ float h_lds[8][NH];       // full h_{t-1} for the 8 batches (32 KB)
  __shared__ float x_lds[8][ND];       // x_t for the 8 batches (8 KB)
  __shared__ float part[4][9][64];     // per-wave reduction stage 0
  __shared__ float part2[4][9][8];     // per-wave reduction stage 1
  __shared__ float xsbuf[4][9][8];     // x-part sums per (wave, row-slot, batch)
  __shared__ float wxb_lds[32];
  __shared__ float whd_lds[32];
  __shared__ float usr_lds[32];
  __shared__ float sbuf[8];            // gate s per batch
  __shared__ float4 obuf[8][32];       // (h, h_tilde, h_prev) per (batch,row)

  // ---- preload weights into registers (held for all 512 steps) ----
  float4 wh[8][4];   // Wh slice: 8 rows x 16 k per thread = 128 VGPR
  float4 wx4[8];     // Wx slice: 8 rows x 4 d per thread
  #pragma unroll
  for (int i = 0; i < 8; ++i) {
    const int rg = r_base + w*8 + i;
    #pragma unroll
    for (int j = 0; j < 4; ++j)
      wh[i][j] = *(const float4*)(Wh_w + (size_t)rg*NH + (kc*4 + j*256));
    wx4[i] = *(const float4*)(Wx_w + (size_t)rg*ND + kc*4);
  }
  float4 us4[4];
  #pragma unroll
  for (int j = 0; j < 4; ++j) us4[j] = *(const float4*)(Us_w + kc*4 + j*256);
  const float4 ws4 = *(const float4*)(Ws_w + kc*4);
  const float wsb  = Ws_b[0];
  if (tid < 32) {
    const int rg = r_base + tid;
    wxb_lds[tid] = Wx_b[rg];
    whd_lds[tid] = Wh_w[(size_t)rg*NH + rg];
    usr_lds[tid] = Us_w[rg];
  }
  __syncthreads();

  float* const hs_o = out + (size_t)NB*NT;                 // ys is [B,T] = 32768
  float* const g_o  = hs_o + (size_t)NB*NT*NH;
  float* const l_o  = g_o  + (size_t)NB*NT*NH;
  float* const r_o  = l_o  + (size_t)NB*NT*NH;

  // 9-slot (8 rows + gate) 64-lane reduction, wave-local (no __syncthreads).
  auto reduce9 = [&](const float* acc) -> float {
    #pragma unroll
    for (int i = 0; i < 9; ++i) part[w][i][kc] = acc[i];
    asm volatile("s_waitcnt lgkmcnt(0)" ::: "memory");
    {
      const int r1 = kc >> 3, seg = kc & 7;
      float s1 = 0.f;
      #pragma unroll
      for (int j = 0; j < 8; ++j) s1 += part[w][r1][seg*8 + j];
      part2[w][r1][seg] = s1;
      if (kc < 8) {
        float su = 0.f;
        #pragma unroll
        for (int j = 0; j < 8; ++j) su += part[w][8][kc*8 + j];
        part2[w][8][kc] = su;
      }
    }
    asm volatile("s_waitcnt lgkmcnt(0)" ::: "memory");
    float tot = 0.f;
    if (kc < 9) {
      #pragma unroll
      for (int s2 = 0; s2 < 8; ++s2) tot += part2[w][kc][s2];
    }
    return tot;   // valid on lanes 0..8 (8 = gate slot)
  };

  for (int t = 0; t < NT; ++t) {
    // ---- stage x_t (no dependency on recurrence) ----
    #pragma unroll
    for (int i = 0; i < 2; ++i) {
      const int f4 = tid + i*256;
      const int bb = f4 >> 6;
      const int d4 = f4 & 63;
      *(float4*)(&x_lds[bb][d4*4]) =
        *(const float4*)(x + ((size_t)(b_base+bb)*NT + t)*ND + d4*4);
    }
    __syncthreads();

    // ---- x-part (Wx.x + Ws.x), computed BEFORE waiting on h_{t-1} ----
    for (int b = 0; b < 8; ++b) {
      const float4 x4 = *(const float4*)(&x_lds[b][kc*4]);
      float acc[9];
      #pragma unroll
      for (int i = 0; i < 8; ++i)
        acc[i] = wx4[i].x*x4.x + wx4[i].y*x4.y + wx4[i].z*x4.z + wx4[i].w*x4.w;
      acc[8] = ws4.x*x4.x + ws4.y*x4.y + ws4.z*x4.z + ws4.w*x4.w;
      const float v = reduce9(acc);
      if (kc < 9) xsbuf[w][kc][b] = v;
    }

    // ---- wait for all 32 slices of h_{t-1}, then stage it ----
    if (t > 0) {
      if (w == 0) {
        const unsigned int* fr = flags + ((size_t)bg*NT + (t-1))*32;
        const int fi = kc & 31;
        while (true) {
          unsigned int v = __hip_atomic_load(fr + fi, __ATOMIC_RELAXED,
                                             __HIP_MEMORY_SCOPE_AGENT);
          if (__all((int)(v != 0u))) break;
          __builtin_amdgcn_s_sleep(1);
        }
        __threadfence();   // acquire: invalidate L1/L2 before reading h data
      }
      __syncthreads();
      const float* src = hbuf + ((size_t)((t-1)&1)*NB + b_base)*NH;
      #pragma unroll
      for (int i = 0; i < 8; ++i) {
        const int f4 = tid + i*256;
        *(float4*)((float*)h_lds + f4*4) = *(const float4*)(src + f4*4);
      }
      __syncthreads();
    }

    // ---- recurrent matmul + gate + state update ----
    const int p = t & 1;
    for (int b = 0; b < 8; ++b) {
      float acc[9];
      #pragma unroll
      for (int i = 0; i < 9; ++i) acc[i] = 0.f;
      if (t > 0) {
        #pragma unroll
        for (int j = 0; j < 4; ++j) {
          const float4 h4 = *(const float4*)(&h_lds[b][kc*4 + j*256]);
          #pragma unroll
          for (int i = 0; i < 8; ++i)
            acc[i] += wh[i][j].x*h4.x + wh[i][j].y*h4.y +
                      wh[i][j].z*h4.z + wh[i][j].w*h4.w;
          acc[8] += us4[j].x*h4.x + us4[j].y*h4.y + us4[j].z*h4.z + us4[j].w*h4.w;
        }
      }
      float tot = reduce9(acc);
      if (kc < 9) tot += xsbuf[w][kc][b];
      const float gsum = __shfl(tot, 8, 64);     // broadcast gate pre-activation
      if (kc < 8) {
        const int rl = w*8 + kc;
        const int rg = r_base + rl;
        const float a    = gsum + wsb;
        const float s    = 1.f / (1.f + expf(-a));
        const float pre  = tot + wxb_lds[rl];
        const float htld = tanhf(pre);
        const float hp   = (t > 0) ? h_lds[b][rg] : 0.f;
        const float h    = (1.f - s)*hp + s*htld;
        hbuf[((size_t)p*NB + (b_base+b))*NH + rg] = h;
        obuf[b][rl] = make_float4(h, htld, hp, 0.f);
        if (kc == 0) sbuf[b] = s;
      }
    }
    __threadfence();      // drain h stores to coherence point
    __syncthreads();
    if (tid == 0)
      __hip_atomic_store(flags + ((size_t)bg*NT + t)*32 + sl, 1u,
                         __ATOMIC_RELEASE, __HIP_MEMORY_SCOPE_AGENT);

    // ---- outputs: off the critical path (after signal), coalesced 128B runs ----
    {
      const int b = w*2 + (kc >> 5);
      const int r = kc & 31;
      const float4 o = obuf[b][r];
      const float s  = sbuf[b];
      const size_t base = ((size_t)(b_base+b)*NT + t)*NH + (r_base + r);
      const float sp = s * (1.f - s);
      hs_o[base] = o.x;
      g_o[base]  = s;
      l_o[base]  = 1.f - s;
      r_o[base]  = (o.y - o.z)*(sp*usr_lds[r]) + s*(1.f - o.y*o.y)*whd_lds[r];
    }
  }
}

// ys[b,t] = out_w . hs[b,t,:] + out_b  (reads hs already in d_out)
__global__ void yfinish_kernel(const float* __restrict__ hs,
                               const float* __restrict__ out_w,
                               const float* __restrict__ out_b,
                               float* __restrict__ ys)
{
  const int row  = (int)blockIdx.x*4 + ((int)threadIdx.x >> 6);
  const int lane = (int)threadIdx.x & 63;
  const float4* hp = (const float4*)(hs + (size_t)row*NH);
  const float4* wp = (const float4*)out_w;
  float s = 0.f;
  #pragma unroll
  for (int i = 0; i < 4; ++i) {
    const float4 h4 = hp[i*64 + lane];
    const float4 w4 = wp[i*64 + lane];
    s += h4.x*w4.x + h4.y*w4.y + h4.z*w4.z + h4.w*w4.w;
  }
  #pragma unroll
  for (int off = 32; off > 0; off >>= 1) s += __shfl_xor(s, off, 64);
  if (lane == 0) ys[row] = s + out_b[0];
}

extern "C" void kernel_launch(void* const* d_in, const int* in_sizes, int n_in,
                              void* d_out, int out_size, void* d_ws, size_t ws_size,
                              hipStream_t stream)
{
  (void)in_sizes; (void)n_in; (void)out_size; (void)ws_size;
  const float* x     = (const float*)d_in[0];
  const float* Wx_w  = (const float*)d_in[1];
  const float* Wx_b  = (const float*)d_in[2];
  const float* Wh_w  = (const float*)d_in[3];
  const float* Ws_w  = (const float*)d_in[4];
  const float* Ws_b  = (const float*)d_in[5];
  const float* Us_w  = (const float*)d_in[6];
  const float* out_w = (const float*)d_in[7];
  const float* out_b = (const float*)d_in[8];
  float* out = (float*)d_out;

  char* ws = (char*)d_ws;
  float* hbuf = (float*)ws;                                  // 2*64*1024*4 = 512 KB
  unsigned int* flags = (unsigned int*)(ws + (size_t)2*NB*NH*4); // 8*512*32*4 = 512 KB

  hipMemsetAsync(flags, 0, (size_t)8*NT*32*sizeof(unsigned int), stream);
  rnn_step_kernel<<<dim3(256), dim3(256), 0, stream>>>(
      x, Wx_w, Wx_b, Wh_w, Ws_w, Ws_b, Us_w, out_w, out, hbuf, flags);
  yfinish_kernel<<<dim3((NB*NT)/4), dim3(256), 0, stream>>>(
      out + (size_t)NB*NT, out_w, out_b, out);
}

// Round 2
// 5713.501 us; speedup vs baseline: 3.1242x; 3.1242x over previous
//
#include <hip/hip_runtime.h>

#define NT 512
#define ND 256
#define NH 1024
#define NB 64

// Grid: 256 wgs = 8 batch-groups (8 batches each) x 32 H-slices (32 rows each).
// Block: 256 threads = 4 waves; wave w owns rows w*8..w*8+7 of the slice,
// lane kc (0..63) owns k-values {kc*4 + j*256 + m : j<4, m<4}.
// Cross-wg handoff of h is done entirely at LLC scope (sc0 sc1 accesses) —
// NO __threadfence (agent fence = full L2 wb/inv = ~10us each, was 2x/step).
__global__ void __launch_bounds__(256, 1)
rnn_step_kernel(const float* __restrict__ x,
                const float* __restrict__ Wx_w,
                const float* __restrict__ Wx_b,
                const float* __restrict__ Wh_w,
                const float* __restrict__ Ws_w,
                const float* __restrict__ Ws_b,
                const float* __restrict__ Us_w,
                float* __restrict__ out,
                float* __restrict__ hbuf,
                unsigned int* __restrict__ flags)
{
  const int tid = (int)threadIdx.x;
  const int w   = tid >> 6;        // wave 0..3
  const int kc  = tid & 63;        // lane
  const int bid = (int)blockIdx.x;
  const int sl  = bid & 31;        // H-slice
  const int bg  = bid >> 5;        // batch group
  const int r_base = sl * 32;
  const int b_base = bg * 8;

  __shared__ float h_lds[8][NH];       // full h_{t-1} for the 8 batches (32 KB)
  __shared__ float x_lds[8][ND];       // x_t for the 8 batches (8 KB)
  __shared__ float part[4][9][65];     // pad 65: stage-1 bank = (r1+seg*8+j)%32 -> 2-way
  __shared__ float part2[4][9][8];
  __shared__ float xsbuf[4][9][8];     // reduced x-part sums per (wave, slot, batch)
  __shared__ float wxb_lds[32];
  __shared__ float whd_lds[32];
  __shared__ float usr_lds[32];
  __shared__ float sbuf[8];            // gate s per batch
  __shared__ float4 obuf[8][32];       // (h, h_tilde, h_prev) per (batch,row)

  // ---- preload weights into registers (held for all 512 steps) ----
  float4 wh[8][4];   // Wh slice: 8 rows x 16 k per thread
  float4 wx4[8];     // Wx slice: 8 rows x 4 d per thread
  #pragma unroll
  for (int i = 0; i < 8; ++i) {
    const int rg = r_base + w*8 + i;
    #pragma unroll
    for (int j = 0; j < 4; ++j)
      wh[i][j] = *(const float4*)(Wh_w + (size_t)rg*NH + (kc*4 + j*256));
    wx4[i] = *(const float4*)(Wx_w + (size_t)rg*ND + kc*4);
  }
  float4 us4[4];
  #pragma unroll
  for (int j = 0; j < 4; ++j) us4[j] = *(const float4*)(Us_w + kc*4 + j*256);
  const float4 ws4 = *(const float4*)(Ws_w + kc*4);
  const float wsb  = Ws_b[0];
  if (tid < 32) {
    const int rg = r_base + tid;
    wxb_lds[tid] = Wx_b[rg];
    whd_lds[tid] = Wh_w[(size_t)rg*NH + rg];
    usr_lds[tid] = Us_w[rg];
  }
  __syncthreads();

  float* const hs_o = out + (size_t)NB*NT;                 // ys is [B,T] = 32768
  float* const g_o  = hs_o + (size_t)NB*NT*NH;
  float* const l_o  = g_o  + (size_t)NB*NT*NH;
  float* const r_o  = l_o  + (size_t)NB*NT*NH;

  // 9-slot (8 rows + gate) 64-lane reduction, wave-local.
  auto reduce9 = [&](const float* acc) -> float {
    #pragma unroll
    for (int i = 0; i < 9; ++i) part[w][i][kc] = acc[i];
    asm volatile("s_waitcnt lgkmcnt(0)" ::: "memory");
    {
      const int r1 = kc >> 3, seg = kc & 7;
      float s1 = 0.f;
      #pragma unroll
      for (int j = 0; j < 8; ++j) s1 += part[w][r1][seg*8 + j];
      part2[w][r1][seg] = s1;
      if (kc < 8) {
        float su = 0.f;
        #pragma unroll
        for (int j = 0; j < 8; ++j) su += part[w][8][kc*8 + j];
        part2[w][8][kc] = su;
      }
    }
    asm volatile("s_waitcnt lgkmcnt(0)" ::: "memory");
    float tot = 0.f;
    if (kc < 9) {
      #pragma unroll
      for (int s2 = 0; s2 < 8; ++s2) tot += part2[w][kc][s2];
    }
    return tot;   // valid on lanes 0..8 (8 = gate slot)
  };

  for (int t = 0; t < NT; ++t) {
    // ---- stage x_t (no dependency on recurrence) ----
    #pragma unroll
    for (int i = 0; i < 2; ++i) {
      const int f4 = tid + i*256;
      const int bb = f4 >> 6;
      const int d4 = f4 & 63;
      *(float4*)(&x_lds[bb][d4*4]) =
        *(const float4*)(x + ((size_t)(b_base+bb)*NT + t)*ND + d4*4);
    }
    __syncthreads();

    // ---- x-part (Wx.x + Ws.x), computed BEFORE waiting on h_{t-1} ----
    for (int b = 0; b < 8; ++b) {
      const float4 x4 = *(const float4*)(&x_lds[b][kc*4]);
      float acc[9];
      #pragma unroll
      for (int i = 0; i < 8; ++i)
        acc[i] = wx4[i].x*x4.x + wx4[i].y*x4.y + wx4[i].z*x4.z + wx4[i].w*x4.w;
      acc[8] = ws4.x*x4.x + ws4.y*x4.y + ws4.z*x4.z + ws4.w*x4.w;
      const float v = reduce9(acc);
      if (kc < 9) xsbuf[w][kc][b] = v;
    }

    // ---- wait for all 32 slices of h_{t-1} (LLC poll), then stage via sc1 loads ----
    if (t > 0) {
      if (w == 0) {
        const unsigned int* fp = flags + ((size_t)bg*NT + (t-1))*32 + (kc & 31);
        while (true) {
          unsigned int v;
          asm volatile("global_load_dword %0, %1, off sc0 sc1\n\t"
                       "s_waitcnt vmcnt(0)"
                       : "=v"(v) : "v"(fp) : "memory");
          if (__all((int)(v != 0u))) break;
          __builtin_amdgcn_s_sleep(1);
        }
      }
      __syncthreads();
      const float* src = hbuf + ((size_t)((t-1)&1)*NB + b_base)*NH;
      float4 hv[8];
      #pragma unroll
      for (int i = 0; i < 8; ++i) {
        const float* a = src + (size_t)(tid + i*256)*4;
        asm volatile("global_load_dwordx4 %0, %1, off sc0 sc1"
                     : "=v"(hv[i]) : "v"(a) : "memory");
      }
      asm volatile("s_waitcnt vmcnt(0)" ::: "memory");
      __builtin_amdgcn_sched_barrier(0);
      #pragma unroll
      for (int i = 0; i < 8; ++i)
        *(float4*)((float*)h_lds + (size_t)(tid + i*256)*4) = hv[i];
      __syncthreads();
    }

    // ---- recurrent matmul + gate + state update ----
    const int p = t & 1;
    for (int b = 0; b < 8; ++b) {
      float acc[9];
      #pragma unroll
      for (int i = 0; i < 9; ++i) acc[i] = 0.f;
      if (t > 0) {
        #pragma unroll
        for (int j = 0; j < 4; ++j) {
          const float4 h4 = *(const float4*)(&h_lds[b][kc*4 + j*256]);
          #pragma unroll
          for (int i = 0; i < 8; ++i)
            acc[i] += wh[i][j].x*h4.x + wh[i][j].y*h4.y +
                      wh[i][j].z*h4.z + wh[i][j].w*h4.w;
          acc[8] += us4[j].x*h4.x + us4[j].y*h4.y + us4[j].z*h4.z + us4[j].w*h4.w;
        }
      }
      float tot = reduce9(acc);
      if (kc < 9) tot += xsbuf[w][kc][b];
      const float gsum = __shfl(tot, 8, 64);     // broadcast gate pre-activation
      if (kc < 8) {
        const int rl = w*8 + kc;
        const int rg = r_base + rl;
        const float a    = gsum + wsb;
        const float s    = 1.f / (1.f + expf(-a));
        const float pre  = tot + wxb_lds[rl];
        const float htld = tanhf(pre);
        const float hp   = (t > 0) ? h_lds[b][rg] : 0.f;
        const float h    = (1.f - s)*hp + s*htld;
        // write-through to LLC so consumers see it without any L2 fence
        float* hptr = hbuf + ((size_t)p*NB + (b_base+b))*NH + rg;
        asm volatile("global_store_dword %0, %1, off sc0 sc1"
                     :: "v"(hptr), "v"(h) : "memory");
        obuf[b][rl] = make_float4(h, htld, hp, 0.f);
        if (kc == 0) sbuf[b] = s;
      }
    }
    // __syncthreads drains vmcnt(0) -> all sc1 h-stores have reached LLC
    __syncthreads();
    if (tid == 0) {
      unsigned int one = 1u;
      unsigned int* fp = flags + ((size_t)bg*NT + t)*32 + sl;
      asm volatile("global_store_dword %0, %1, off sc0 sc1"
                   :: "v"(fp), "v"(one) : "memory");
    }

    // ---- outputs: off the critical path (after signal), non-temporal ----
    {
      const int b = w*2 + (kc >> 5);
      const int r = kc & 31;
      const float4 o = obuf[b][r];
      const float s  = sbuf[b];
      const size_t base = ((size_t)(b_base+b)*NT + t)*NH + (r_base + r);
      const float sp = s * (1.f - s);
      __builtin_nontemporal_store(o.x, &hs_o[base]);
      __builtin_nontemporal_store(s, &g_o[base]);
      __builtin_nontemporal_store(1.f - s, &l_o[base]);
      __builtin_nontemporal_store((o.y - o.z)*(sp*usr_lds[r]) + s*(1.f - o.y*o.y)*whd_lds[r],
                                  &r_o[base]);
    }
  }
}

// ys[b,t] = out_w . hs[b,t,:] + out_b  (reads hs already in d_out)
__global__ void yfinish_kernel(const float* __restrict__ hs,
                               const float* __restrict__ out_w,
                               const float* __restrict__ out_b,
                               float* __restrict__ ys)
{
  const int row  = (int)blockIdx.x*4 + ((int)threadIdx.x >> 6);
  const int lane = (int)threadIdx.x & 63;
  const float4* hp = (const float4*)(hs + (size_t)row*NH);
  const float4* wp = (const float4*)out_w;
  float s = 0.f;
  #pragma unroll
  for (int i = 0; i < 4; ++i) {
    const float4 h4 = hp[i*64 + lane];
    const float4 w4 = wp[i*64 + lane];
    s += h4.x*w4.x + h4.y*w4.y + h4.z*w4.z + h4.w*w4.w;
  }
  #pragma unroll
  for (int off = 32; off > 0; off >>= 1) s += __shfl_xor(s, off, 64);
  if (lane == 0) ys[row] = s + out_b[0];
}

extern "C" void kernel_launch(void* const* d_in, const int* in_sizes, int n_in,
                              void* d_out, int out_size, void* d_ws, size_t ws_size,
                              hipStream_t stream)
{
  (void)in_sizes; (void)n_in; (void)out_size; (void)ws_size;
  const float* x     = (const float*)d_in[0];
  const float* Wx_w  = (const float*)d_in[1];
  const float* Wx_b  = (const float*)d_in[2];
  const float* Wh_w  = (const float*)d_in[3];
  const float* Ws_w  = (const float*)d_in[4];
  const float* Ws_b  = (const float*)d_in[5];
  const float* Us_w  = (const float*)d_in[6];
  const float* out_w = (const float*)d_in[7];
  const float* out_b = (const float*)d_in[8];
  float* out = (float*)d_out;

  char* ws = (char*)d_ws;
  float* hbuf = (float*)ws;                                      // 512 KB
  unsigned int* flags = (unsigned int*)(ws + (size_t)2*NB*NH*4); // 512 KB

  hipMemsetAsync(flags, 0, (size_t)8*NT*32*sizeof(unsigned int), stream);
  rnn_step_kernel<<<dim3(256), dim3(256), 0, stream>>>(
      x, Wx_w, Wx_b, Wh_w, Ws_w, Ws_b, Us_w, out, hbuf, flags);
  yfinish_kernel<<<dim3((NB*NT)/4), dim3(256), 0, stream>>>(
      out + (size_t)NB*NT, out_w, out_b, out);
}